// Round 1
// baseline (618.582 us; speedup 1.0000x reference)
//
#include <hip/hip_runtime.h>
#include <cstdint>
#include <cstddef>

// Problem constants (B=4, S=4096, D=1024, Din=2048)
#define BB 4
#define SS 4096
#define DD 1024
#define DIN 2048
#define MTOT (BB*SS)        // 16384 rows
#define K1 DD               // GEMM1 K = 1024
#define K2 DIN              // GEMM2 K = 2048
#define N2 DD               // GEMM2 N = 1024
#define NCH (BB*DIN)        // 8192 scan channels
#define NCHUNK 32
#define CLEN (SS/NCHUNK)    // 128

typedef _Float16 half8  __attribute__((ext_vector_type(8)));
typedef _Float16 half4v __attribute__((ext_vector_type(4)));
typedef float    floatx4 __attribute__((ext_vector_type(4)));

// generic->addrspace casts (CK-style int round-trip; LDS flat addr low 32 bits = LDS offset)
#define AS1(p) ((__attribute__((address_space(1))) void*)(uintptr_t)(p))
#define AS3(p) ((__attribute__((address_space(3))) void*)(uint32_t)(uintptr_t)(p))

__device__ __forceinline__ void gload16(const void* g, void* l) {
  // async global->LDS, 16B/lane; LDS dest = wave-uniform base + lane*16
  __builtin_amdgcn_global_load_lds(AS1(g), AS3(l), 16, 0, 0);
}

__device__ __forceinline__ float sigm(float x) { return 1.f / (1.f + __expf(-x)); }
__device__ __forceinline__ float softp(float x) {
  return fmaxf(x, 0.f) + __logf(1.f + __expf(-fabsf(x)));
}
__device__ __forceinline__ uint32_t hbits(float f) {
  _Float16 h = (_Float16)f; uint16_t u; __builtin_memcpy(&u, &h, 2); return (uint32_t)u;
}
__device__ __forceinline__ float h_lo(uint32_t v) {
  uint16_t u = (uint16_t)(v & 0xffffu); _Float16 h; __builtin_memcpy(&h, &u, 2); return (float)h;
}
__device__ __forceinline__ float h_hi(uint32_t v) {
  uint16_t u = (uint16_t)(v >> 16); _Float16 h; __builtin_memcpy(&h, &u, 2); return (float)h;
}

// ---------------- elementwise converts ----------------

__global__ void f32_to_f16_vec(const float* __restrict__ src, _Float16* __restrict__ dst) {
  int i = (blockIdx.x * blockDim.x + threadIdx.x) * 4;
  float4 v = *(const float4*)(src + i);
  half4v o; o.x = (_Float16)v.x; o.y = (_Float16)v.y; o.z = (_Float16)v.z; o.w = (_Float16)v.w;
  *(half4v*)(dst + i) = o;
}

// src[R][C] f32 -> dst[C][R] f16
__global__ void transpose_cvt(const float* __restrict__ src, _Float16* __restrict__ dst,
                              int R, int C) {
  __shared__ float t[32][33];
  int c0 = blockIdx.x * 32, r0 = blockIdx.y * 32;
  int tx = threadIdx.x, ty = threadIdx.y;
#pragma unroll
  for (int j = 0; j < 32; j += 8)
    t[ty + j][tx] = src[(size_t)(r0 + ty + j) * C + c0 + tx];
  __syncthreads();
#pragma unroll
  for (int j = 0; j < 32; j += 8)
    dst[(size_t)(c0 + ty + j) * R + r0 + tx] = (_Float16)t[tx][ty + j];
}

// ---------------- GEMM1: x @ W1 fused with gate math ----------------
// Block tile: 128 rows (m) x 64 features (d); computes hidden/forget/input tiles
// for the SAME (m,d) range -> lane-local gate fusion in epilogue.
// A = xh [MTOT][K1], B^T = w1t [3*DIN][K1]; out: packed (z|g<<16) fp16 pairs.
__global__ __launch_bounds__(256) void gemm1_fused(
    const _Float16* __restrict__ xh, const _Float16* __restrict__ w1t,
    const float* __restrict__ b1, uint32_t* __restrict__ zg) {
  __shared__ _Float16 As[128 * 32];      // [row][k], 8 KB
  __shared__ _Float16 Bs[3][64 * 32];    // [n][k] per gate, 12 KB

  const int tid = threadIdx.x;
  const int wave = tid >> 6, lane = tid & 63;
  const int wm = wave >> 1, wn = wave & 1;     // 2x2 waves: 64 rows x 32 cols each
  const int m0 = blockIdx.y * 128;
  const int d0 = blockIdx.x * 64;
  const int lrow = lane >> 2;                  // 0..15: row within 16-row chunk
  const int lk = (lane & 3) * 8;               // k element offset of this lane's 16B
  const int kq = (lane >> 4) * 8;              // frag k offset (quad*8)

  floatx4 acc[3][4][2] = {};

  for (int k0 = 0; k0 < K1; k0 += 32) {
    __syncthreads();
    // stage A: 8KB = 8 chunks of 1KB (16 rows each); 2 chunks per wave
#pragma unroll
    for (int i = 0; i < 2; ++i) {
      int chunk = wave * 2 + i;
      const _Float16* g = xh + (size_t)(m0 + chunk * 16 + lrow) * K1 + k0 + lk;
      gload16(g, As + chunk * 512);
    }
    // stage B: 3 gate tiles, 4KB each = 1 chunk per wave per gate
#pragma unroll
    for (int gt = 0; gt < 3; ++gt) {
      const _Float16* g = w1t + (size_t)(gt * DIN + d0 + wave * 16 + lrow) * K1 + k0 + lk;
      gload16(g, &Bs[gt][wave * 512]);
    }
    __syncthreads();

    half8 af[4], bfr[3][2];
#pragma unroll
    for (int mi = 0; mi < 4; ++mi)
      af[mi] = *(const half8*)(As + (wm * 64 + mi * 16 + (lane & 15)) * 32 + kq);
#pragma unroll
    for (int gt = 0; gt < 3; ++gt)
#pragma unroll
      for (int ni = 0; ni < 2; ++ni)
        bfr[gt][ni] = *(const half8*)(&Bs[gt][(wn * 32 + ni * 16 + (lane & 15)) * 32 + kq]);
#pragma unroll
    for (int gt = 0; gt < 3; ++gt)
#pragma unroll
      for (int mi = 0; mi < 4; ++mi)
#pragma unroll
        for (int ni = 0; ni < 2; ++ni)
          acc[gt][mi][ni] = __builtin_amdgcn_mfma_f32_16x16x32_f16(
              af[mi], bfr[gt][ni], acc[gt][mi][ni], 0, 0, 0);
  }

  // epilogue: bias + gate math, write packed (z,g)
#pragma unroll
  for (int ni = 0; ni < 2; ++ni) {
    int d = d0 + wn * 32 + ni * 16 + (lane & 15);
    float bh = b1[d], bf_ = b1[DIN + d], bi = b1[2 * DIN + d];
#pragma unroll
    for (int mi = 0; mi < 4; ++mi) {
#pragma unroll
      for (int r = 0; r < 4; ++r) {
        int m = m0 + wm * 64 + mi * 16 + (lane >> 4) * 4 + r;
        float hv = acc[0][mi][ni][r] + bh;
        float fv = acc[1][mi][ni][r] + bf_;
        float iv = acc[2][mi][ni][r] + bi;
        float dff = softp(-fv) - softp(-iv);
        float z = sigm(dff);
        float gg = (hv >= 0.f) ? (hv + 0.5f) : sigm(hv);
        zg[(size_t)m * DIN + d] = hbits(z) | (hbits(gg) << 16);
      }
    }
  }
}

// ---------------- chunked parallel scan: h_t = (1-z) h + z g ----------------

__global__ void scanA(const uint32_t* __restrict__ zg,
                      float* __restrict__ cA, float* __restrict__ cB) {
  int gidx = blockIdx.x * 256 + threadIdx.x;
  int q = gidx >> 13, c = gidx & (NCH - 1);
  int b = c >> 11, d = c & (DIN - 1);
  size_t base = ((size_t)b * SS + q * CLEN) * DIN + d;
  float A = 1.f, Bv = 0.f;
#pragma unroll 4
  for (int t = 0; t < CLEN; ++t) {
    uint32_t v = zg[base + (size_t)t * DIN];
    float z = h_lo(v), g = h_hi(v);
    A *= (1.f - z);
    Bv = fmaf(z, g - Bv, Bv);
  }
  cA[q * NCH + c] = A;
  cB[q * NCH + c] = Bv;
}

__global__ void scanB(const float* __restrict__ cA, const float* __restrict__ cB,
                      const float* __restrict__ init_h, float* __restrict__ cH) {
  int c = blockIdx.x * 256 + threadIdx.x;  // 8192 channels
  int d = c & (DIN - 1);
  float x = init_h[d];
  float h = (x >= 0.f) ? (x + 0.5f) : sigm(x);  // h0 = g(init_h), same for all b
#pragma unroll
  for (int q = 0; q < NCHUNK; ++q) {
    cH[q * NCH + c] = h;                        // h at START of chunk q
    h = fmaf(cA[q * NCH + c], h, cB[q * NCH + c]);
  }
}

__global__ void scanC(const uint32_t* __restrict__ zg, const float* __restrict__ cH,
                      _Float16* __restrict__ hh, float* __restrict__ out_tail) {
  int gidx = blockIdx.x * 256 + threadIdx.x;
  int q = gidx >> 13, c = gidx & (NCH - 1);
  int b = c >> 11, d = c & (DIN - 1);
  size_t base = ((size_t)b * SS + q * CLEN) * DIN + d;
  float h = cH[q * NCH + c];
#pragma unroll 4
  for (int t = 0; t < CLEN; ++t) {
    uint32_t v = zg[base + (size_t)t * DIN];
    float z = h_lo(v), g = h_hi(v);
    h = fmaf(z, g - h, h);
    hh[base + (size_t)t * DIN] = (_Float16)h;
  }
  if (q == NCHUNK - 1) {
    out_tail[c] = h;             // next_hidden
    out_tail[NCH + c] = logf(h); // next_log_hidden
  }
}

// ---------------- GEMM2: out_h @ W2 + b2 (m97-style 128x128) ----------------
__global__ __launch_bounds__(256) void gemm2k(
    const _Float16* __restrict__ hh, const _Float16* __restrict__ w2t,
    const float* __restrict__ b2, float* __restrict__ out) {
  __shared__ _Float16 As[128 * 32];
  __shared__ _Float16 Bs[128 * 32];

  const int tid = threadIdx.x;
  const int wave = tid >> 6, lane = tid & 63;
  const int wm = wave >> 1, wn = wave & 1;     // 2x2 waves: 64x64 each
  const int m0 = blockIdx.y * 128;
  const int n0 = blockIdx.x * 128;
  const int lrow = lane >> 2;
  const int lk = (lane & 3) * 8;
  const int kq = (lane >> 4) * 8;

  floatx4 acc[4][4] = {};

  for (int k0 = 0; k0 < K2; k0 += 32) {
    __syncthreads();
#pragma unroll
    for (int i = 0; i < 2; ++i) {
      int chunk = wave * 2 + i;
      const _Float16* gA = hh + (size_t)(m0 + chunk * 16 + lrow) * K2 + k0 + lk;
      gload16(gA, As + chunk * 512);
      const _Float16* gB = w2t + (size_t)(n0 + chunk * 16 + lrow) * K2 + k0 + lk;
      gload16(gB, Bs + chunk * 512);
    }
    __syncthreads();

    half8 af[4], bfr[4];
#pragma unroll
    for (int mi = 0; mi < 4; ++mi)
      af[mi] = *(const half8*)(As + (wm * 64 + mi * 16 + (lane & 15)) * 32 + kq);
#pragma unroll
    for (int ni = 0; ni < 4; ++ni)
      bfr[ni] = *(const half8*)(Bs + (wn * 64 + ni * 16 + (lane & 15)) * 32 + kq);
#pragma unroll
    for (int mi = 0; mi < 4; ++mi)
#pragma unroll
      for (int ni = 0; ni < 4; ++ni)
        acc[mi][ni] = __builtin_amdgcn_mfma_f32_16x16x32_f16(af[mi], bfr[ni], acc[mi][ni], 0, 0, 0);
  }

#pragma unroll
  for (int ni = 0; ni < 4; ++ni) {
    int n = n0 + wn * 64 + ni * 16 + (lane & 15);
    float bias = b2[n];
#pragma unroll
    for (int mi = 0; mi < 4; ++mi) {
#pragma unroll
      for (int r = 0; r < 4; ++r) {
        int m = m0 + wm * 64 + mi * 16 + (lane >> 4) * 4 + r;
        out[(size_t)m * N2 + n] = acc[mi][ni][r] + bias;
      }
    }
  }
}

// ---------------- launch ----------------

extern "C" void kernel_launch(void* const* d_in, const int* in_sizes, int n_in,
                              void* d_out, int out_size, void* d_ws, size_t ws_size,
                              hipStream_t stream) {
  const float* x      = (const float*)d_in[0];
  const float* W1     = (const float*)d_in[1];
  const float* b1     = (const float*)d_in[2];
  const float* W2     = (const float*)d_in[3];
  const float* b2     = (const float*)d_in[4];
  const float* init_h = (const float*)d_in[5];
  float* out = (float*)d_out;

  char* w = (char*)d_ws;
  _Float16* xh  = (_Float16*)w; w += (size_t)MTOT * K1 * 2;       // 32 MB
  _Float16* w1t = (_Float16*)w; w += (size_t)3 * DIN * K1 * 2;    // 12 MB
  _Float16* w2t = (_Float16*)w; w += (size_t)N2 * K2 * 2;         // 4 MB
  uint32_t* zg  = (uint32_t*)w; w += (size_t)MTOT * DIN * 4;      // 128 MB
  _Float16* hh  = (_Float16*)w; w += (size_t)MTOT * DIN * 2;      // 64 MB
  float* cA = (float*)w; w += (size_t)NCH * NCHUNK * 4;
  float* cB = (float*)w; w += (size_t)NCH * NCHUNK * 4;
  float* cH = (float*)w; w += (size_t)NCH * NCHUNK * 4;

  f32_to_f16_vec<<<dim3(MTOT * K1 / 1024), dim3(256), 0, stream>>>(x, xh);
  transpose_cvt<<<dim3(3 * DIN / 32, K1 / 32), dim3(32, 8), 0, stream>>>(W1, w1t, K1, 3 * DIN);
  transpose_cvt<<<dim3(N2 / 32, K2 / 32), dim3(32, 8), 0, stream>>>(W2, w2t, K2, N2);

  gemm1_fused<<<dim3(DIN / 64, MTOT / 128), dim3(256), 0, stream>>>(xh, w1t, b1, zg);

  scanA<<<dim3(NCH * NCHUNK / 256), dim3(256), 0, stream>>>(zg, cA, cB);
  scanB<<<dim3(NCH / 256), dim3(256), 0, stream>>>(cA, cB, init_h, cH);
  scanC<<<dim3(NCH * NCHUNK / 256), dim3(256), 0, stream>>>(zg, cH, hh, out + (size_t)MTOT * DD);

  gemm2k<<<dim3(N2 / 128, MTOT / 128), dim3(256), 0, stream>>>(hh, w2t, b2, out);
}

// Round 3
// 593.995 us; speedup vs baseline: 1.0414x; 1.0414x over previous
//
#include <hip/hip_runtime.h>
#include <cstdint>
#include <cstddef>

// Problem constants (B=4, S=4096, D=1024, Din=2048)
#define BB 4
#define SS 4096
#define DD 1024
#define DIN 2048
#define MTOT (BB*SS)        // 16384 rows
#define K1 DD               // GEMM1 K = 1024
#define K2 DIN              // GEMM2 K = 2048
#define N2 DD               // GEMM2 N = 1024
#define NCH (BB*DIN)        // 8192 scan channels
#define NCHUNK 32
#define CLEN (SS/NCHUNK)    // 128

typedef _Float16 half8  __attribute__((ext_vector_type(8)));
typedef _Float16 half4v __attribute__((ext_vector_type(4)));
typedef float    floatx4 __attribute__((ext_vector_type(4)));

#define AS1(p) ((__attribute__((address_space(1))) void*)(uintptr_t)(p))
#define AS3(p) ((__attribute__((address_space(3))) void*)(uint32_t)(uintptr_t)(p))

__device__ __forceinline__ void gload16(const void* g, void* l) {
  // async global->LDS, 16B/lane; LDS dest = wave-uniform base + lane*16
  __builtin_amdgcn_global_load_lds(AS1(g), AS3(l), 16, 0, 0);
}

__device__ __forceinline__ float sigm(float x) { return 1.f / (1.f + __expf(-x)); }
__device__ __forceinline__ uint32_t hbits(float f) {
  _Float16 h = (_Float16)f; uint16_t u; __builtin_memcpy(&u, &h, 2); return (uint32_t)u;
}
__device__ __forceinline__ float h_lo(uint32_t v) {
  uint16_t u = (uint16_t)(v & 0xffffu); _Float16 h; __builtin_memcpy(&h, &u, 2); return (float)h;
}
__device__ __forceinline__ float h_hi(uint32_t v) {
  uint16_t u = (uint16_t)(v >> 16); _Float16 h; __builtin_memcpy(&h, &u, 2); return (float)h;
}

// ---------------- elementwise converts ----------------

__global__ void f32_to_f16_vec(const float* __restrict__ src, _Float16* __restrict__ dst) {
  int i = (blockIdx.x * blockDim.x + threadIdx.x) * 4;
  float4 v = *(const float4*)(src + i);
  half4v o; o.x = (_Float16)v.x; o.y = (_Float16)v.y; o.z = (_Float16)v.z; o.w = (_Float16)v.w;
  *(half4v*)(dst + i) = o;
}

// src[R][C] f32 -> dst[C][R] f16
__global__ void transpose_cvt(const float* __restrict__ src, _Float16* __restrict__ dst,
                              int R, int C) {
  __shared__ float t[32][33];
  int c0 = blockIdx.x * 32, r0 = blockIdx.y * 32;
  int tx = threadIdx.x, ty = threadIdx.y;
#pragma unroll
  for (int j = 0; j < 32; j += 8)
    t[ty + j][tx] = src[(size_t)(r0 + ty + j) * C + c0 + tx];
  __syncthreads();
#pragma unroll
  for (int j = 0; j < 32; j += 8)
    dst[(size_t)(c0 + ty + j) * R + r0 + tx] = (_Float16)t[tx][ty + j];
}

// ---------------- GEMM1: x @ W1 fused with gate math ----------------
// Staging: lane l fetches (row = l>>2, kg = (l&3)^((l>>2)&3)) of a 16-row chunk;
// 4 consecutive lanes <-> one contiguous 64B row segment (R1-proven transaction
// shape). LDS granule g thus holds (row=g>>2, kg=(g&3)^((g>>2)&3)): the XOR
// swizzle makes fragment reads 2-way-conflict max (free per m136) instead of 8-way.
// Read: lane l wants (row=l&15, kq=l>>4) -> granule (l&15)*4 + ((l>>4)^(l&3)).
__global__ __launch_bounds__(256) void gemm1_fused(
    const _Float16* __restrict__ xh, const _Float16* __restrict__ w1t,
    const float* __restrict__ b1, uint32_t* __restrict__ zg) {
  __shared__ _Float16 As[128 * 32];      // 8 chunks x 1KB
  __shared__ _Float16 Bs[3][64 * 32];    // per gate: 4 chunks x 1KB

  const int tid = threadIdx.x;
  const int wave = tid >> 6, lane = tid & 63;
  const int wm = wave >> 1, wn = wave & 1;     // 2x2 waves: 64 rows x 32 cols/gate
  const int m0 = blockIdx.y * 128;
  const int d0 = blockIdx.x * 64;
  const int lrow = lane >> 2;                              // staged row in chunk
  const int lk = (((lane & 3) ^ (lrow & 3)) * 8);          // staged k offset (halfs)
  const int roff = ((((lane & 15) << 2) | ((lane >> 4) ^ (lane & 3))) * 8); // read offset (halfs)

  floatx4 acc[3][4][2] = {};

  for (int k0 = 0; k0 < K1; k0 += 32) {
    __syncthreads();
#pragma unroll
    for (int i = 0; i < 2; ++i) {
      int chunk = wave * 2 + i;
      gload16(xh + (size_t)(m0 + chunk * 16 + lrow) * K1 + k0 + lk, As + chunk * 512);
    }
#pragma unroll
    for (int gt = 0; gt < 3; ++gt)
      gload16(w1t + (size_t)(gt * DIN + d0 + wave * 16 + lrow) * K1 + k0 + lk,
              &Bs[gt][wave * 512]);
    asm volatile("s_waitcnt vmcnt(0)" ::: "memory");
    __syncthreads();

    half8 af[4], bfr[3][2];
#pragma unroll
    for (int mi = 0; mi < 4; ++mi)
      af[mi] = *(const half8*)(As + (wm * 4 + mi) * 512 + roff);
#pragma unroll
    for (int gt = 0; gt < 3; ++gt)
#pragma unroll
      for (int ni = 0; ni < 2; ++ni)
        bfr[gt][ni] = *(const half8*)(&Bs[gt][(wn * 2 + ni) * 512 + roff]);
#pragma unroll
    for (int gt = 0; gt < 3; ++gt)
#pragma unroll
      for (int mi = 0; mi < 4; ++mi)
#pragma unroll
        for (int ni = 0; ni < 2; ++ni)
          acc[gt][mi][ni] = __builtin_amdgcn_mfma_f32_16x16x32_f16(
              af[mi], bfr[gt][ni], acc[gt][mi][ni], 0, 0, 0);
  }

  // epilogue: bias + gate math, write packed (z,g)
  // z = sigma(softplus(-f)-softplus(-i)) = u/(u+v), u=1+e^-f, v=1+e^-i
#pragma unroll
  for (int ni = 0; ni < 2; ++ni) {
    int d = d0 + wn * 32 + ni * 16 + (lane & 15);
    float bh = b1[d], bf_ = b1[DIN + d], bi = b1[2 * DIN + d];
#pragma unroll
    for (int mi = 0; mi < 4; ++mi) {
#pragma unroll
      for (int r = 0; r < 4; ++r) {
        int m = m0 + wm * 64 + mi * 16 + (lane >> 4) * 4 + r;
        float hv = acc[0][mi][ni][r] + bh;
        float fv = acc[1][mi][ni][r] + bf_;
        float iv = acc[2][mi][ni][r] + bi;
        float u = 1.f + __expf(-fminf(fmaxf(fv, -30.f), 30.f));
        float v = 1.f + __expf(-fminf(fmaxf(iv, -30.f), 30.f));
        float z = __fdividef(u, u + v);
        float gg = (hv >= 0.f) ? (hv + 0.5f)
                               : __fdividef(1.f, 1.f + __expf(-fmaxf(hv, -30.f)));
        zg[(size_t)m * DIN + d] = hbits(z) | (hbits(gg) << 16);
      }
    }
  }
}

// ---------------- chunked parallel scan: h_t = (1-z) h + z g ----------------

__global__ void scanA(const uint32_t* __restrict__ zg,
                      float* __restrict__ cA, float* __restrict__ cB) {
  int gidx = blockIdx.x * 256 + threadIdx.x;
  int q = gidx >> 13, c = gidx & (NCH - 1);
  int b = c >> 11, d = c & (DIN - 1);
  size_t base = ((size_t)b * SS + q * CLEN) * DIN + d;
  float A = 1.f, Bv = 0.f;
#pragma unroll 4
  for (int t = 0; t < CLEN; ++t) {
    uint32_t v = zg[base + (size_t)t * DIN];
    float z = h_lo(v), g = h_hi(v);
    A *= (1.f - z);
    Bv = fmaf(z, g - Bv, Bv);
  }
  cA[q * NCH + c] = A;
  cB[q * NCH + c] = Bv;
}

__global__ void scanB(const float* __restrict__ cA, const float* __restrict__ cB,
                      const float* __restrict__ init_h, float* __restrict__ cH) {
  int c = blockIdx.x * 256 + threadIdx.x;  // 8192 channels
  int d = c & (DIN - 1);
  float x = init_h[d];
  float h = (x >= 0.f) ? (x + 0.5f) : sigm(x);  // h0 = g(init_h)
#pragma unroll
  for (int q = 0; q < NCHUNK; ++q) {
    cH[q * NCH + c] = h;                        // h at START of chunk q
    h = fmaf(cA[q * NCH + c], h, cB[q * NCH + c]);
  }
}

__global__ void scanC(const uint32_t* __restrict__ zg, const float* __restrict__ cH,
                      _Float16* __restrict__ hh, float* __restrict__ out_tail) {
  int gidx = blockIdx.x * 256 + threadIdx.x;
  int q = gidx >> 13, c = gidx & (NCH - 1);
  int b = c >> 11, d = c & (DIN - 1);
  size_t base = ((size_t)b * SS + q * CLEN) * DIN + d;
  float h = cH[q * NCH + c];
#pragma unroll 4
  for (int t = 0; t < CLEN; ++t) {
    uint32_t v = zg[base + (size_t)t * DIN];
    float z = h_lo(v), g = h_hi(v);
    h = fmaf(z, g - h, h);
    hh[base + (size_t)t * DIN] = (_Float16)h;
  }
  if (q == NCHUNK - 1) {
    out_tail[c] = h;             // next_hidden
    out_tail[NCH + c] = logf(h); // next_log_hidden
  }
}

// ---------------- GEMM2: out_h @ W2 + b2 (128x128, swizzled LDS) ---------
__global__ __launch_bounds__(256) void gemm2k(
    const _Float16* __restrict__ hh, const _Float16* __restrict__ w2t,
    const float* __restrict__ b2, float* __restrict__ out) {
  __shared__ _Float16 As[128 * 32];
  __shared__ _Float16 Bs[128 * 32];

  const int tid = threadIdx.x;
  const int wave = tid >> 6, lane = tid & 63;
  const int wm = wave >> 1, wn = wave & 1;     // 2x2 waves: 64x64 each
  const int m0 = blockIdx.y * 128;
  const int n0 = blockIdx.x * 128;
  const int lrow = lane >> 2;
  const int lk = (((lane & 3) ^ (lrow & 3)) * 8);
  const int roff = ((((lane & 15) << 2) | ((lane >> 4) ^ (lane & 3))) * 8);

  floatx4 acc[4][4] = {};

  for (int k0 = 0; k0 < K2; k0 += 32) {
    __syncthreads();
#pragma unroll
    for (int i = 0; i < 2; ++i) {
      int chunk = wave * 2 + i;
      gload16(hh  + (size_t)(m0 + chunk * 16 + lrow) * K2 + k0 + lk, As + chunk * 512);
      gload16(w2t + (size_t)(n0 + chunk * 16 + lrow) * K2 + k0 + lk, Bs + chunk * 512);
    }
    asm volatile("s_waitcnt vmcnt(0)" ::: "memory");
    __syncthreads();

    half8 af[4], bfr[4];
#pragma unroll
    for (int mi = 0; mi < 4; ++mi)
      af[mi] = *(const half8*)(As + (wm * 4 + mi) * 512 + roff);
#pragma unroll
    for (int ni = 0; ni < 4; ++ni)
      bfr[ni] = *(const half8*)(Bs + (wn * 4 + ni) * 512 + roff);
#pragma unroll
    for (int mi = 0; mi < 4; ++mi)
#pragma unroll
      for (int ni = 0; ni < 4; ++ni)
        acc[mi][ni] = __builtin_amdgcn_mfma_f32_16x16x32_f16(af[mi], bfr[ni], acc[mi][ni], 0, 0, 0);
  }

#pragma unroll
  for (int ni = 0; ni < 4; ++ni) {
    int n = n0 + wn * 64 + ni * 16 + (lane & 15);
    float bias = b2[n];
#pragma unroll
    for (int mi = 0; mi < 4; ++mi) {
#pragma unroll
      for (int r = 0; r < 4; ++r) {
        int m = m0 + wm * 64 + mi * 16 + (lane >> 4) * 4 + r;
        out[(size_t)m * N2 + n] = acc[mi][ni][r] + bias;
      }
    }
  }
}

// ---------------- launch ----------------

extern "C" void kernel_launch(void* const* d_in, const int* in_sizes, int n_in,
                              void* d_out, int out_size, void* d_ws, size_t ws_size,
                              hipStream_t stream) {
  const float* x      = (const float*)d_in[0];
  const float* W1     = (const float*)d_in[1];
  const float* b1     = (const float*)d_in[2];
  const float* W2     = (const float*)d_in[3];
  const float* b2     = (const float*)d_in[4];
  const float* init_h = (const float*)d_in[5];
  float* out = (float*)d_out;

  char* w = (char*)d_ws;
  _Float16* xh  = (_Float16*)w; w += (size_t)MTOT * K1 * 2;       // 32 MB
  _Float16* w1t = (_Float16*)w; w += (size_t)3 * DIN * K1 * 2;    // 12 MB
  _Float16* w2t = (_Float16*)w; w += (size_t)N2 * K2 * 2;         // 4 MB
  uint32_t* zg  = (uint32_t*)w; w += (size_t)MTOT * DIN * 4;      // 128 MB
  _Float16* hh  = (_Float16*)w; w += (size_t)MTOT * DIN * 2;      // 64 MB
  float* cA = (float*)w; w += (size_t)NCH * NCHUNK * 4;
  float* cB = (float*)w; w += (size_t)NCH * NCHUNK * 4;
  float* cH = (float*)w; w += (size_t)NCH * NCHUNK * 4;

  f32_to_f16_vec<<<dim3(MTOT * K1 / 1024), dim3(256), 0, stream>>>(x, xh);
  transpose_cvt<<<dim3(3 * DIN / 32, K1 / 32), dim3(32, 8), 0, stream>>>(W1, w1t, K1, 3 * DIN);
  transpose_cvt<<<dim3(N2 / 32, K2 / 32), dim3(32, 8), 0, stream>>>(W2, w2t, K2, N2);

  gemm1_fused<<<dim3(DIN / 64, MTOT / 128), dim3(256), 0, stream>>>(xh, w1t, b1, zg);

  scanA<<<dim3(NCH * NCHUNK / 256), dim3(256), 0, stream>>>(zg, cA, cB);
  scanB<<<dim3(NCH / 256), dim3(256), 0, stream>>>(cA, cB, init_h, cH);
  scanC<<<dim3(NCH * NCHUNK / 256), dim3(256), 0, stream>>>(zg, cH, hh, out + (size_t)MTOT * DD);

  gemm2k<<<dim3(N2 / 128, MTOT / 128), dim3(256), 0, stream>>>(hh, w2t, b2, out);
}